// Round 3
// baseline (43.861 us; speedup 1.0000x reference)
//
#include <hip/hip_runtime.h>
#include <stdint.h>

#define NF    64
#define DIM0  50000
#define SROWS 100000
#define ROW_DW 16   // 64B row: 8 dw codes + 2 dw sums + 6 dw pad

// ---------------------------------------------------------------------------
// Pass 1: closed-form quantize + per-row partial sums, packed 64B rows.
//   q = clamp(ceil(16*f - 1), 0, 15)   (bit-exact vs argmin incl. tie->lower)
//   row layout: [0..8) codes (4-bit x64), [8..10) float2 sums, [10..16) pad
//   axis0 row: sums = { Sum_{f<32}(X'A + C), Sum_{f>=32}(X'A + C) }
//   axis1 row: sums = { Sum_{f<32}(Y'B),     Sum_{f>=32}(Y'B) }
// where W=V0-V1-V2+V3, X'=W/512+(V1-V3)/16, Y'=W/512+(V2-V3)/16,
//       C = W/1024 + (V1+V2-2*V3)/32 + V3
// 8 threads per row (8 feats each), shuffle-reduce the sums.
// ---------------------------------------------------------------------------
__global__ void quantize_kernel(const float* __restrict__ feats,
                                const float* __restrict__ values,
                                uint32_t* __restrict__ rows) {
    __shared__ float sT0[NF];  // X'
    __shared__ float sT1[NF];  // Y'
    __shared__ float sC[NF];   // constant (folded into axis0)
    int t = threadIdx.x;
    if (t < NF) {
        float v0 = values[t], v1 = values[NF + t];
        float v2 = values[2 * NF + t], v3 = values[3 * NF + t];
        float W = v0 - v1 - v2 + v3;
        float X = v1 - v3, Y = v2 - v3;
        sT0[t] = W * (1.0f / 512.0f) + X * (1.0f / 16.0f);
        sT1[t] = W * (1.0f / 512.0f) + Y * (1.0f / 16.0f);
        sC[t]  = W * (1.0f / 1024.0f) + (X + Y) * (1.0f / 32.0f) + v3;
    }
    __syncthreads();

    int gid = blockIdx.x * blockDim.x + t;   // word index: s*8 + w (exact grid)
    int s = gid >> 3;
    int w = gid & 7;
    bool axis0 = (s < DIM0);

    const float4* fr = (const float4*)(feats + (size_t)s * NF + w * 8);
    float4 fA = fr[0], fB = fr[1];
    float fv[8] = {fA.x, fA.y, fA.z, fA.w, fB.x, fB.y, fB.z, fB.w};

    uint32_t word = 0u;
    float partial = 0.0f;
#pragma unroll
    for (int j = 0; j < 8; ++j) {
        int f = w * 8 + j;
        float x = fmaf(fv[j], 16.0f, -1.0f);   // exact: 16f-1 representable
        int q = (int)ceilf(x);
        q = q < 0 ? 0 : (q > 15 ? 15 : q);
        word |= (uint32_t)q << (4 * j);
        float T = axis0 ? sT0[f] : sT1[f];
        partial = fmaf(T, (float)q, partial);
        if (axis0) partial += sC[f];
    }
    uint32_t* row = rows + (size_t)s * ROW_DW;
    row[w] = word;

    // reduce the 4 threads of each half (w 0..3 -> f<32, w 4..7 -> f>=32)
    partial += __shfl_xor(partial, 1);
    partial += __shfl_xor(partial, 2);
    float other = __shfl_xor(partial, 4);
    if (w == 0) *(float2*)(row + 8) = make_float2(partial, other);
}

// ---------------------------------------------------------------------------
// Pass 2: per-query cross term + packed row sums (1 cache line per row).
//   asum = Sum_{f<32} W'_f A_f B_f + sa.x + sb.x
//   bsum = Sum_{f>=32} ...        + sa.y + sb.y
//   out  = asum * tanh(bsum) * exp(scale) + bias
// ---------------------------------------------------------------------------
__global__ void query_kernel(const uint32_t* __restrict__ rows,
                             const float* __restrict__ values,
                             const float* __restrict__ scale,
                             const float* __restrict__ bias,
                             const int* __restrict__ idx0,
                             const int* __restrict__ idx1,
                             float* __restrict__ out, int N) {
    __shared__ float sW[NF];   // W' = (V0-V1-V2+V3)/256
    if (threadIdx.x < NF) {
        int t = threadIdx.x;
        float v0 = values[t], v1 = values[NF + t];
        float v2 = values[2 * NF + t], v3 = values[3 * NF + t];
        sW[t] = (v0 - v1 - v2 + v3) * (1.0f / 256.0f);
    }
    __syncthreads();

    int n = blockIdx.x * blockDim.x + threadIdx.x;
    if (n >= N) return;

    const uint32_t* r0 = rows + (size_t)idx0[n] * ROW_DW;
    const uint32_t* r1 = rows + (size_t)(DIM0 + idx1[n]) * ROW_DW;

    uint4 a0 = *(const uint4*)(r0);
    uint4 a1 = *(const uint4*)(r0 + 4);
    float2 sa = *(const float2*)(r0 + 8);
    uint4 b0 = *(const uint4*)(r1);
    uint4 b1 = *(const uint4*)(r1 + 4);
    float2 sb = *(const float2*)(r1 + 8);

    uint32_t aw[8] = {a0.x, a0.y, a0.z, a0.w, a1.x, a1.y, a1.z, a1.w};
    uint32_t bw[8] = {b0.x, b0.y, b0.z, b0.w, b1.x, b1.y, b1.z, b1.w};

    float ca = 0.0f, cb = 0.0f;
#pragma unroll
    for (int wd = 0; wd < 8; ++wd) {
        uint32_t wa = aw[wd];
        uint32_t wb = bw[wd];
#pragma unroll
        for (int j = 0; j < 8; ++j) {
            int f = wd * 8 + j;
            uint32_t A = (wa >> (4 * j)) & 15u;
            uint32_t B = (wb >> (4 * j)) & 15u;
            float p = (float)(A * B);                 // exact, <= 225
            if (f < 32) ca = fmaf(p, sW[f], ca);
            else        cb = fmaf(p, sW[f], cb);
        }
    }

    float asum = ca + sa.x + sb.x;
    float bsum = cb + sa.y + sb.y;
    out[n] = asum * tanhf(bsum) * expf(scale[0]) + bias[0];
}

extern "C" void kernel_launch(void* const* d_in, const int* in_sizes, int n_in,
                              void* d_out, int out_size, void* d_ws, size_t ws_size,
                              hipStream_t stream) {
    const float* values = (const float*)d_in[0];  // [1,4,64]
    const float* feats  = (const float*)d_in[1];  // [100000,64]
    const float* scale  = (const float*)d_in[3];  // [1]
    const float* bias   = (const float*)d_in[4];  // [1]
    const int*   idx0   = (const int*)d_in[5];    // [N]
    const int*   idx1   = (const int*)d_in[6];    // [N]
    float*       out    = (float*)d_out;          // [N] f32

    uint32_t* rows = (uint32_t*)d_ws;             // SROWS * 64B = 6.4 MB

    int tpb = 256;
    int nwords = SROWS * 8;                        // 800000 = 3125 * 256 exact
    quantize_kernel<<<nwords / tpb, tpb, 0, stream>>>(feats, values, rows);

    int N = out_size;
    query_kernel<<<(N + tpb - 1) / tpb, tpb, 0, stream>>>(
        rows, values, scale, bias, idx0, idx1, out, N);
}